// Round 11
// baseline (175.851 us; speedup 1.0000x reference)
//
#include <hip/hip_runtime.h>

// messages: [B=64, E=4096, D=128] f32 ; tgt: [B,E] int32 in [0,N=512)
// out: [B, N, D] f32 segment-sum.
// R11: sequential-stream + LDS-slab scatter. Block = (batch, D-quarter).
// Streams its batch's message quarter-columns SEQUENTIALLY (128B line per
// half-wave, every line read once device-wide), scatter-adds into a 64KiB
// [N][32] LDS slab (conflict-free banks), then writes the slab out once.
// No binning phase, no global atomics (R9: global-atomic scatter = 453us).
constexpr int B = 64, E = 4096, N = 512, D = 128;
constexpr int THREADS = 512;
constexpr int QCOLS = 32;                 // D columns owned per block
constexpr int NBLK = B * (D / QCOLS);     // 256 blocks: (batch, quarter)
constexpr int ITERS = E * QCOLS / THREADS;// 256 (f32 items per thread)
constexpr int U = 8;                      // unroll: 8 loads in flight/thread

__global__ __launch_bounds__(THREADS)
void stream_slab(const float* __restrict__ msgs,
                 const int* __restrict__ tgt,
                 float* __restrict__ out) {
    __shared__ float slab[N * QCOLS];     // 64 KiB

    const int tid = threadIdx.x;
    const int b   = blockIdx.x >> 2;
    const int c0  = (blockIdx.x & 3) * QCOLS;

    // ---- zero slab ----
    float4* s4 = reinterpret_cast<float4*>(slab);
    #pragma unroll
    for (int i = 0; i < (N * QCOLS / 4) / THREADS; ++i)
        s4[i * THREADS + tid] = make_float4(0.f, 0.f, 0.f, 0.f);
    __syncthreads();

    // ---- stream + LDS scatter ----
    // thread -> (edge e, col l): l = tid&31, e = it*16 + (tid>>5)
    const int l      = tid & 31;
    const int e_base = tid >> 5;          // 0..15
    const int* tb = tgt + b * E;
    const float* mb = msgs + (size_t)b * E * D + c0;

    for (int it = 0; it < ITERS; it += U) {
        float v[U]; int n[U];
        #pragma unroll
        for (int j = 0; j < U; ++j) {     // 8 independent 128B-seg loads
            const int e = (it + j) * 16 + e_base;
            v[j] = mb[(size_t)e * D + l];
            n[j] = tb[e];                 // half-wave broadcast
        }
        #pragma unroll
        for (int j = 0; j < U; ++j)       // distinct banks per half-wave
            atomicAdd(&slab[n[j] * QCOLS + l], v[j]);
    }
    __syncthreads();

    // ---- epilogue: write slab to out[b][n][c0..c0+31] (exactly once) ----
    const int f4    = tid & 7;            // float4 index within 32 cols
    const int nrow0 = tid >> 3;           // 0..63
    const float4* sl4 = reinterpret_cast<const float4*>(slab);
    #pragma unroll
    for (int i = 0; i < N / 64; ++i) {
        const int n = i * 64 + nrow0;
        reinterpret_cast<float4*>(out + ((size_t)(b * N + n)) * D + c0)[f4]
            = sl4[n * 8 + f4];            // 128B contiguous per 8-lane group
    }
}

extern "C" void kernel_launch(void* const* d_in, const int* in_sizes, int n_in,
                              void* d_out, int out_size, void* d_ws, size_t ws_size,
                              hipStream_t stream) {
    const float* msgs = (const float*)d_in[0];
    const int*   tgt  = (const int*)d_in[1];
    float* out = (float*)d_out;
    stream_slab<<<NBLK, THREADS, 0, stream>>>(msgs, tgt, out);
}

// Round 12
// 32.843 us; speedup vs baseline: 5.3543x; 5.3543x over previous
//
#include <hip/hip_runtime.h>

// messages: [B=64, E=4096, D=128] f32 ; tgt: [B,E] int32 in [0,N=512)
// out: [B, N, D] f32 segment-sum.
// FINAL (R7 structure, best measured: 32.6-32.9us).
// Block owns (batch b, 64 output rows): single-pass LDS bucket binning
// (1 LDS atomic + 1 LDS write per match), then 8-deep-MLP gather with
// float2 row loads. No global atomics, no workspace, one dispatch.
// Rejected alternatives (measured):
//   R9  global-atomic scatter: 453us (atomic L2-line write-back, WRITE 536MB)
//   R11 sequential-stream + LDS-slab scatter: 176us (LDS-atomic serialization)
//   R6  paired-row float4 loads: 35.6us; R8 dual-seg MLP: 33.1us (neutral)
// Wall: compulsory random-512B row reads (~5 TB/s blended service rate).
constexpr int B = 64, E = 4096, N = 512, D = 128;
constexpr int QN = 64;                 // segs owned per block
constexpr int CAP = 32;                // bucket slots per seg (lambda=8)
constexpr int OVF = 256;               // overflow list capacity (~never hit)
constexpr int THREADS = 512;           // 8 waves
constexpr int EPT = E / THREADS;       // 8 targets scanned per thread
constexpr int NBLK = B * (N / QN);     // 512 blocks

__global__ __launch_bounds__(THREADS)
void fused_seg_sum(const float* __restrict__ msgs,
                   const int* __restrict__ tgt,
                   float* __restrict__ out) {
    __shared__ int cnt[QN];                   // per-seg cursors
    __shared__ unsigned short lst[QN * CAP];  // fixed-slot buckets (4 KiB)
    __shared__ int novf;
    __shared__ unsigned int ovf[OVF];         // (n<<12)|e overflow entries

    const int tid  = threadIdx.x;
    const int lane = tid & 63;
    const int w    = tid >> 6;            // wave 0..7
    const int b    = blockIdx.x >> 3;     // 8 blocks per batch
    const int n0   = (blockIdx.x & 7) * QN;

    if (tid < QN) cnt[tid] = 0;
    if (tid == THREADS - 1) novf = 0;
    __syncthreads();

    // ---- single-pass binning: 1 LDS atomic + 1 LDS write per match ----
    const int* tb = tgt + b * E;
    #pragma unroll
    for (int t = 0; t < EPT; ++t) {
        const int n = tb[t * THREADS + tid] - n0;       // coalesced idx read
        if ((unsigned)n < (unsigned)QN) {
            const int e = t * THREADS + tid;
            const int slot = atomicAdd(&cnt[n], 1);
            if (slot < CAP) lst[n * CAP + slot] = (unsigned short)e;
            else {                                       // ~never taken
                const int o = atomicAdd(&novf, 1);
                if (o < OVF) ovf[o] = ((unsigned)n << 12) | (unsigned)e;
            }
        }
    }
    __syncthreads();

    // ---- gather: wave w owns segs n0+w*8 .. +7 ----
    const float2* mb = reinterpret_cast<const float2*>(msgs) + (size_t)b * E * 64;
    float2* ob = reinterpret_cast<float2*>(out) + ((size_t)b * N + n0) * 64;
    const int no = novf;                  // wave-uniform (post-barrier)
    #pragma unroll
    for (int s = 0; s < 8; ++s) {
        const int n = w * 8 + s;
        const int k = min(cnt[n], CAP);
        float ax = 0.f, ay = 0.f;
        for (int i = 0; i < k; i += 8) {           // one iter for typical k<=8
            int ee[8]; float wt[8];
            #pragma unroll
            for (int j = 0; j < 8; ++j) {
                const bool v = (i + j < k);         // wave-uniform
                ee[j] = v ? (int)lst[n * CAP + i + j] : 0;   // LDS broadcast
                wt[j] = v ? 1.f : 0.f;
            }
            float2 vv[8];
            #pragma unroll
            for (int j = 0; j < 8; ++j)             // 8 independent 512B loads
                vv[j] = mb[(size_t)ee[j] * 64 + lane];
            #pragma unroll
            for (int j = 0; j < 8; ++j) { ax += wt[j] * vv[j].x; ay += wt[j] * vv[j].y; }
        }
        if (no) {                                   // overflow safety net (~never)
            for (int o = 0; o < no && o < OVF; ++o) {
                const unsigned v = ovf[o];
                if ((int)(v >> 12) == n) {
                    const float2 r = mb[(size_t)(v & 0xFFFu) * 64 + lane];
                    ax += r.x; ay += r.y;
                }
            }
        }
        float2 r; r.x = ax; r.y = ay;
        ob[(size_t)n * 64 + lane] = r;              // covers every output once
    }
}

extern "C" void kernel_launch(void* const* d_in, const int* in_sizes, int n_in,
                              void* d_out, int out_size, void* d_ws, size_t ws_size,
                              hipStream_t stream) {
    const float* msgs = (const float*)d_in[0];
    const int*   tgt  = (const int*)d_in[1];
    float* out = (float*)d_out;
    fused_seg_sum<<<NBLK, THREADS, 0, stream>>>(msgs, tgt, out);
}